// Round 1
// baseline (8999.447 us; speedup 1.0000x reference)
//
#include <hip/hip_runtime.h>

// QLSTM fused persistent-dataflow kernel for MI355X (gfx950).
// T=256, B=128, D=1024, H=1024. Only gates f,i,g matter (o unused); h==c.
// Phase A: convert x to bf16 (ws). Phase B: one persistent kernel, 256 WGs
// (one per CU, all co-resident), weights held in VGPRs, per-step flag
// handshake (agent-scope atomics + __threadfence) instead of grid sync.

typedef __attribute__((ext_vector_type(8))) short short8;   // 8 x bf16 (4 VGPRs)
typedef __attribute__((ext_vector_type(4))) float f32x4;    // MFMA accumulator

#define TT 256
#define BB 128
#define DD 1024
#define HH 1024

__device__ __forceinline__ unsigned short f2bf(float f) {
  unsigned u = __float_as_uint(f);
  u += 0x7FFFu + ((u >> 16) & 1u);          // RNE
  return (unsigned short)(u >> 16);
}
__device__ __forceinline__ float sigf(float x) {
  return 1.f / (1.f + __expf(-x));
}
__device__ __forceinline__ float tnhf(float x) {
  float e = __expf(2.f * x);                // overflow-safe: e=inf -> 1.0
  return 1.f - 2.f / (e + 1.f);
}

__global__ __launch_bounds__(256) void qlstm_cvt_x(const float* __restrict__ x,
                                                   unsigned short* __restrict__ xb) {
  size_t i = ((size_t)blockIdx.x * 256u + threadIdx.x) * 8u;
  const float4* p = (const float4*)(x + i);
  float4 a = p[0], b = p[1];
  short8 o;
  o[0] = (short)f2bf(a.x); o[1] = (short)f2bf(a.y);
  o[2] = (short)f2bf(a.z); o[3] = (short)f2bf(a.w);
  o[4] = (short)f2bf(b.x); o[5] = (short)f2bf(b.y);
  o[6] = (short)f2bf(b.z); o[7] = (short)f2bf(b.w);
  *(short8*)(xb + i) = o;
}

// 256 WGs x 256 threads. WG = (rg in [0,4), cg in [0,64)):
//   batch rows [32*rg, 32*rg+32), h columns [16*cg, 16*cg+16).
// 4 waves K-split the 1024-wide contraction (256 each) for both the x-part
// (W rows [0,1024)) and h-part (W rows [1024,2048)).
__global__ __launch_bounds__(256, 1) void qlstm_recur(
    const unsigned short* __restrict__ xb,
    const float* __restrict__ Wf, const float* __restrict__ Wi, const float* __restrict__ Wg,
    const float* __restrict__ bf_, const float* __restrict__ bi_, const float* __restrict__ bg_,
    unsigned short* hbuf, unsigned int* flags, float* __restrict__ out) {
  const int wg = blockIdx.x;
  const int rg = wg >> 6, cg = wg & 63;
  const int tid = threadIdx.x;
  const int lane = tid & 63, wave = tid >> 6;
  const int quad = lane >> 4, l15 = lane & 15;

  __shared__ float red[96 * 65];            // 4 waves x 6 frags x 4 regs, padded

  // ---- persistent weight fragments in VGPRs: wfr[part][gate][kstep] ----
  short8 wfr[2][3][8];
  {
    const int ncol = cg * 16 + l15;
    const float* Wm0 = Wf; const float* Wm1 = Wi; const float* Wm2 = Wg;
#pragma unroll
    for (int p = 0; p < 2; ++p)
#pragma unroll
      for (int g = 0; g < 3; ++g) {
        const float* W = (g == 0) ? Wm0 : ((g == 1) ? Wm1 : Wm2);
#pragma unroll
        for (int s = 0; s < 8; ++s) {
          int kbase = p * 1024 + wave * 256 + s * 32 + quad * 8;
          short8 v;
#pragma unroll
          for (int j = 0; j < 8; ++j)
            v[j] = (short)f2bf(W[(size_t)(kbase + j) * HH + ncol]);
          wfr[p][g][s] = v;
        }
      }
  }

  // ---- combine-phase mapping: thread -> (row r, cols ccol, ccol+1) ----
  const int p0 = tid * 2;
  const int r = p0 >> 4, ccol = p0 & 15;    // r in [0,32), ccol even
  const int brow = rg * 32 + r;             // batch row
  const int gcol = cg * 16 + ccol;          // h column
  const int tile = r >> 4, rl = r & 15, q2 = rl >> 2, reg4 = rl & 3;

  float bias0[3], bias1[3];
  bias0[0] = bf_[gcol]; bias1[0] = bf_[gcol + 1];
  bias0[1] = bi_[gcol]; bias1[1] = bi_[gcol + 1];
  bias0[2] = bg_[gcol]; bias1[2] = bg_[gcol + 1];

  float c0 = 0.f, c1 = 0.f;                 // persistent cell state (c==h)
  const f32x4 zero4 = {0.f, 0.f, 0.f, 0.f};

  for (int t = 0; t < TT; ++t) {
    // ---- x-part (no recurrence dependency): issue before flag wait ----
    short8 af[2][8];
#pragma unroll
    for (int s = 0; s < 8; ++s) {
      int k = wave * 256 + s * 32 + quad * 8;
#pragma unroll
      for (int i = 0; i < 2; ++i)
        af[i][s] = *(const short8*)(xb + (size_t)(t * BB + rg * 32 + i * 16 + l15) * DD + k);
    }
    f32x4 acc[2][3];
#pragma unroll
    for (int i = 0; i < 2; ++i)
#pragma unroll
      for (int g = 0; g < 3; ++g) acc[i][g] = zero4;
#pragma unroll
    for (int s = 0; s < 8; ++s)
#pragma unroll
      for (int i = 0; i < 2; ++i)
#pragma unroll
        for (int g = 0; g < 3; ++g)
          acc[i][g] = __builtin_amdgcn_mfma_f32_16x16x32_bf16(af[i][s], wfr[0][g][s], acc[i][g], 0, 0, 0);

    // ---- h-part: wait for previous step's producers in our row-group ----
    if (t > 0) {
      if (tid < 64) {
        const unsigned int* fl = flags + (size_t)(t - 1) * 256 + rg * 64 + tid;
        while (__hip_atomic_load(fl, __ATOMIC_RELAXED, __HIP_MEMORY_SCOPE_AGENT) != (unsigned)t)
          __builtin_amdgcn_s_sleep(2);
      }
      __syncthreads();
      __threadfence();                      // acquire: invalidate caches
      const unsigned short* hb = hbuf + (size_t)((t - 1) & 1) * (BB * HH);
#pragma unroll
      for (int s = 0; s < 8; ++s) {
        int k = wave * 256 + s * 32 + quad * 8;
#pragma unroll
        for (int i = 0; i < 2; ++i)
          af[i][s] = *(const short8*)(hb + (size_t)(rg * 32 + i * 16 + l15) * HH + k);
      }
#pragma unroll
      for (int s = 0; s < 8; ++s)
#pragma unroll
        for (int i = 0; i < 2; ++i)
#pragma unroll
          for (int g = 0; g < 3; ++g)
            acc[i][g] = __builtin_amdgcn_mfma_f32_16x16x32_bf16(af[i][s], wfr[1][g][s], acc[i][g], 0, 0, 0);
    }

    // ---- cross-wave K reduction through LDS ----
#pragma unroll
    for (int i = 0; i < 2; ++i)
#pragma unroll
      for (int g = 0; g < 3; ++g) {
        int fidx = i * 3 + g;
#pragma unroll
        for (int rr = 0; rr < 4; ++rr)
          red[(wave * 24 + fidx * 4 + rr) * 65 + lane] = acc[i][g][rr];
      }
    __syncthreads();

    // ---- combine: z = xW + hW + b; gates; state update ----
    float zz0[3], zz1[3];
#pragma unroll
    for (int g = 0; g < 3; ++g) {
      int fidx = tile * 3 + g;
      float s0 = 0.f, s1 = 0.f;
#pragma unroll
      for (int w = 0; w < 4; ++w) {
        int base = (w * 24 + fidx * 4 + reg4) * 65 + q2 * 16 + ccol;
        s0 += red[base];
        s1 += red[base + 1];
      }
      zz0[g] = s0 + bias0[g];
      zz1[g] = s1 + bias1[g];
    }
    float nv0 = sigf(zz0[0]) * c0 + sigf(zz0[1]) * tnhf(zz0[2]);
    float nv1 = sigf(zz1[0]) * c1 + sigf(zz1[1]) * tnhf(zz1[2]);
    c0 = nv0; c1 = nv1;

    float2 st; st.x = nv0; st.y = nv1;
    *(float2*)(out + (size_t)(t * BB + brow) * HH + gcol) = st;
    unsigned hp = (unsigned)f2bf(nv0) | ((unsigned)f2bf(nv1) << 16);
    *(unsigned*)(hbuf + (size_t)(t & 1) * (BB * HH) + (size_t)brow * HH + gcol) = hp;
    if (t == TT - 1) {                      // final (h, c) outputs
      *(float2*)(out + (size_t)TT * BB * HH + (size_t)brow * HH + gcol) = st;
      *(float2*)(out + (size_t)TT * BB * HH + (size_t)BB * HH + (size_t)brow * HH + gcol) = st;
    }

    __syncthreads();                        // drains vmcnt: h stores in L2
    if (tid == 0) {
      __threadfence();                      // release: flush L2 to coherence point
      __hip_atomic_store(flags + (size_t)t * 256 + wg, (unsigned)(t + 1),
                         __ATOMIC_RELAXED, __HIP_MEMORY_SCOPE_AGENT);
    }
  }
}

extern "C" void kernel_launch(void* const* d_in, const int* in_sizes, int n_in,
                              void* d_out, int out_size, void* d_ws, size_t ws_size,
                              hipStream_t stream) {
  const float* x   = (const float*)d_in[0];
  const float* Wf  = (const float*)d_in[1];
  const float* bf_ = (const float*)d_in[2];
  const float* Wi  = (const float*)d_in[3];
  const float* bi_ = (const float*)d_in[4];
  const float* Wg  = (const float*)d_in[5];
  const float* bg_ = (const float*)d_in[6];
  // d_in[7], d_in[8] = W_o, b_o: unused by the reference's outputs.
  float* out = (float*)d_out;

  char* ws = (char*)d_ws;
  unsigned short* xb = (unsigned short*)(ws);              // 256*128*1024 bf16 = 64 MiB
  unsigned short* hb = (unsigned short*)(ws + 67108864);   // 2*128*1024 bf16 (double buffer)
  unsigned int*   fl = (unsigned int*)(ws + 67633152);     // 256 steps * 256 WG flags
  // total ws use: 67,895,296 bytes

  hipLaunchKernelGGL(qlstm_cvt_x, dim3(16384), dim3(256), 0, stream, x, xb);
  hipLaunchKernelGGL(qlstm_recur, dim3(256), dim3(256), 0, stream,
                     xb, Wf, Wi, Wg, bf_, bi_, bg_, hb, fl, out);
}

// Round 2
// 2340.735 us; speedup vs baseline: 3.8447x; 3.8447x over previous
//
#include <hip/hip_runtime.h>

// QLSTM fused persistent-dataflow kernel for MI355X (gfx950).
// T=256, B=128, D=1024, H=1024. Only gates f,i,g matter (o unused); h==c.
// Phase A: convert x to bf16 (ws). Phase B: one persistent kernel, 256 WGs
// (one per CU, all co-resident), weights held in VGPRs.
// R2: cross-WG handshake via relaxed AGENT-scope atomics on BOTH flags and
// hbuf (sc-annotated, coherent at Infinity Cache) — NO __threadfence(), so
// no buffer_inv/buffer_wbl2 in the loop. Ordering via __syncthreads()'s
// vmcnt(0) drain before the flag publish.

typedef __attribute__((ext_vector_type(8))) short short8;   // 8 x bf16 (4 VGPRs)
typedef __attribute__((ext_vector_type(4))) float f32x4;    // MFMA accumulator

#define TT 256
#define BB 128
#define DD 1024
#define HH 1024

__device__ __forceinline__ unsigned short f2bf(float f) {
  unsigned u = __float_as_uint(f);
  u += 0x7FFFu + ((u >> 16) & 1u);          // RNE
  return (unsigned short)(u >> 16);
}
__device__ __forceinline__ float sigf(float x) {
  return 1.f / (1.f + __expf(-x));
}
__device__ __forceinline__ float tnhf(float x) {
  float e = __expf(2.f * x);                // overflow-safe: e=inf -> 1.0
  return 1.f - 2.f / (e + 1.f);
}

__global__ __launch_bounds__(256) void qlstm_cvt_x(const float* __restrict__ x,
                                                   unsigned short* __restrict__ xb) {
  size_t i = ((size_t)blockIdx.x * 256u + threadIdx.x) * 8u;
  const float4* p = (const float4*)(x + i);
  float4 a = p[0], b = p[1];
  short8 o;
  o[0] = (short)f2bf(a.x); o[1] = (short)f2bf(a.y);
  o[2] = (short)f2bf(a.z); o[3] = (short)f2bf(a.w);
  o[4] = (short)f2bf(b.x); o[5] = (short)f2bf(b.y);
  o[6] = (short)f2bf(b.z); o[7] = (short)f2bf(b.w);
  *(short8*)(xb + i) = o;
}

// 256 WGs x 256 threads. WG = (rg in [0,4), cg in [0,64)):
//   batch rows [32*rg, 32*rg+32), h columns [16*cg, 16*cg+16).
// 4 waves K-split the 1024-wide contraction (256 each) for both the x-part
// (W rows [0,1024)) and h-part (W rows [1024,2048)).
__global__ __launch_bounds__(256, 1) void qlstm_recur(
    const unsigned short* __restrict__ xb,
    const float* __restrict__ Wf, const float* __restrict__ Wi, const float* __restrict__ Wg,
    const float* __restrict__ bf_, const float* __restrict__ bi_, const float* __restrict__ bg_,
    unsigned short* hbuf, unsigned int* flags, float* __restrict__ out) {
  const int wg = blockIdx.x;
  const int rg = wg >> 6, cg = wg & 63;
  const int tid = threadIdx.x;
  const int lane = tid & 63, wave = tid >> 6;
  const int quad = lane >> 4, l15 = lane & 15;

  __shared__ float red[96 * 65];            // 4 waves x 6 frags x 4 regs, padded

  // ---- persistent weight fragments in VGPRs: wfr[part][gate][kstep] ----
  short8 wfr[2][3][8];
  {
    const int ncol = cg * 16 + l15;
    const float* Wm0 = Wf; const float* Wm1 = Wi; const float* Wm2 = Wg;
#pragma unroll
    for (int p = 0; p < 2; ++p)
#pragma unroll
      for (int g = 0; g < 3; ++g) {
        const float* W = (g == 0) ? Wm0 : ((g == 1) ? Wm1 : Wm2);
#pragma unroll
        for (int s = 0; s < 8; ++s) {
          int kbase = p * 1024 + wave * 256 + s * 32 + quad * 8;
          short8 v;
#pragma unroll
          for (int j = 0; j < 8; ++j)
            v[j] = (short)f2bf(W[(size_t)(kbase + j) * HH + ncol]);
          wfr[p][g][s] = v;
        }
      }
  }

  // ---- combine-phase mapping: thread -> (row r, cols ccol, ccol+1) ----
  const int p0 = tid * 2;
  const int r = p0 >> 4, ccol = p0 & 15;    // r in [0,32), ccol even
  const int brow = rg * 32 + r;             // batch row
  const int gcol = cg * 16 + ccol;          // h column
  const int tile = r >> 4, rl = r & 15, q2 = rl >> 2, reg4 = rl & 3;

  float bias0[3], bias1[3];
  bias0[0] = bf_[gcol]; bias1[0] = bf_[gcol + 1];
  bias0[1] = bi_[gcol]; bias1[1] = bi_[gcol + 1];
  bias0[2] = bg_[gcol]; bias1[2] = bg_[gcol + 1];

  float c0 = 0.f, c1 = 0.f;                 // persistent cell state (c==h)
  const f32x4 zero4 = {0.f, 0.f, 0.f, 0.f};

  for (int t = 0; t < TT; ++t) {
    // ---- x-part (no recurrence dependency): issue before flag wait ----
    short8 af[2][8];
#pragma unroll
    for (int s = 0; s < 8; ++s) {
      int k = wave * 256 + s * 32 + quad * 8;
#pragma unroll
      for (int i = 0; i < 2; ++i)
        af[i][s] = *(const short8*)(xb + (size_t)(t * BB + rg * 32 + i * 16 + l15) * DD + k);
    }
    f32x4 acc[2][3];
#pragma unroll
    for (int i = 0; i < 2; ++i)
#pragma unroll
      for (int g = 0; g < 3; ++g) acc[i][g] = zero4;
#pragma unroll
    for (int s = 0; s < 8; ++s)
#pragma unroll
      for (int i = 0; i < 2; ++i)
#pragma unroll
        for (int g = 0; g < 3; ++g)
          acc[i][g] = __builtin_amdgcn_mfma_f32_16x16x32_bf16(af[i][s], wfr[0][g][s], acc[i][g], 0, 0, 0);

    // ---- h-part: wait for previous step's producers in our row-group ----
    if (t > 0) {
      if (tid < 64) {
        const unsigned int* fl = flags + (size_t)(t - 1) * 256 + rg * 64 + tid;
        while (__hip_atomic_load(fl, __ATOMIC_RELAXED, __HIP_MEMORY_SCOPE_AGENT) != (unsigned)t)
          __builtin_amdgcn_s_sleep(1);
      }
      __syncthreads();                      // all consumers see flags == t
      const unsigned short* hb = hbuf + (size_t)((t - 1) & 1) * (BB * HH);
#pragma unroll
      for (int s = 0; s < 8; ++s) {
        int k = wave * 256 + s * 32 + quad * 8;
#pragma unroll
        for (int i = 0; i < 2; ++i) {
          const unsigned long long* q =
              (const unsigned long long*)(hb + (size_t)(rg * 32 + i * 16 + l15) * HH + k);
          union { unsigned long long u[2]; short8 s8; } cv;
          cv.u[0] = __hip_atomic_load(q,     __ATOMIC_RELAXED, __HIP_MEMORY_SCOPE_AGENT);
          cv.u[1] = __hip_atomic_load(q + 1, __ATOMIC_RELAXED, __HIP_MEMORY_SCOPE_AGENT);
          af[i][s] = cv.s8;
        }
      }
#pragma unroll
      for (int s = 0; s < 8; ++s)
#pragma unroll
        for (int i = 0; i < 2; ++i)
#pragma unroll
          for (int g = 0; g < 3; ++g)
            acc[i][g] = __builtin_amdgcn_mfma_f32_16x16x32_bf16(af[i][s], wfr[1][g][s], acc[i][g], 0, 0, 0);
    }

    // ---- cross-wave K reduction through LDS ----
#pragma unroll
    for (int i = 0; i < 2; ++i)
#pragma unroll
      for (int g = 0; g < 3; ++g) {
        int fidx = i * 3 + g;
#pragma unroll
        for (int rr = 0; rr < 4; ++rr)
          red[(wave * 24 + fidx * 4 + rr) * 65 + lane] = acc[i][g][rr];
      }
    __syncthreads();

    // ---- combine: z = xW + hW + b; gates; state update ----
    float zz0[3], zz1[3];
#pragma unroll
    for (int g = 0; g < 3; ++g) {
      int fidx = tile * 3 + g;
      float s0 = 0.f, s1 = 0.f;
#pragma unroll
      for (int w = 0; w < 4; ++w) {
        int base = (w * 24 + fidx * 4 + reg4) * 65 + q2 * 16 + ccol;
        s0 += red[base];
        s1 += red[base + 1];
      }
      zz0[g] = s0 + bias0[g];
      zz1[g] = s1 + bias1[g];
    }
    float nv0 = sigf(zz0[0]) * c0 + sigf(zz0[1]) * tnhf(zz0[2]);
    float nv1 = sigf(zz1[0]) * c1 + sigf(zz1[1]) * tnhf(zz1[2]);
    c0 = nv0; c1 = nv1;

    float2 st; st.x = nv0; st.y = nv1;
    *(float2*)(out + (size_t)(t * BB + brow) * HH + gcol) = st;
    if (t < TT - 1) {
      // publish h via coherent (agent-scope) store — lands at Infinity Cache
      unsigned hp = (unsigned)f2bf(nv0) | ((unsigned)f2bf(nv1) << 16);
      unsigned* hq = (unsigned*)(hbuf + (size_t)(t & 1) * (BB * HH) + (size_t)brow * HH + gcol);
      __hip_atomic_store(hq, hp, __ATOMIC_RELAXED, __HIP_MEMORY_SCOPE_AGENT);
    } else {                                // final (h, c) outputs
      *(float2*)(out + (size_t)TT * BB * HH + (size_t)brow * HH + gcol) = st;
      *(float2*)(out + (size_t)TT * BB * HH + (size_t)BB * HH + (size_t)brow * HH + gcol) = st;
    }

    // __syncthreads drains vmcnt(0): every thread's h store is ack'd at the
    // coherence point before tid0 publishes the flag. LDS `red` reuse next
    // iteration is also protected by this barrier.
    __syncthreads();
    if (t < TT - 1 && tid == 0) {
      __hip_atomic_store(flags + (size_t)t * 256 + wg, (unsigned)(t + 1),
                         __ATOMIC_RELAXED, __HIP_MEMORY_SCOPE_AGENT);
    }
  }
}

extern "C" void kernel_launch(void* const* d_in, const int* in_sizes, int n_in,
                              void* d_out, int out_size, void* d_ws, size_t ws_size,
                              hipStream_t stream) {
  const float* x   = (const float*)d_in[0];
  const float* Wf  = (const float*)d_in[1];
  const float* bf_ = (const float*)d_in[2];
  const float* Wi  = (const float*)d_in[3];
  const float* bi_ = (const float*)d_in[4];
  const float* Wg  = (const float*)d_in[5];
  const float* bg_ = (const float*)d_in[6];
  // d_in[7], d_in[8] = W_o, b_o: unused by the reference's outputs.
  float* out = (float*)d_out;

  char* ws = (char*)d_ws;
  unsigned short* xb = (unsigned short*)(ws);              // 256*128*1024 bf16 = 64 MiB
  unsigned short* hb = (unsigned short*)(ws + 67108864);   // 2*128*1024 bf16 (double buffer)
  unsigned int*   fl = (unsigned int*)(ws + 67633152);     // 256 steps * 256 WG flags
  // total ws use: 67,895,296 bytes

  hipLaunchKernelGGL(qlstm_cvt_x, dim3(16384), dim3(256), 0, stream, x, xb);
  hipLaunchKernelGGL(qlstm_recur, dim3(256), dim3(256), 0, stream,
                     xb, Wf, Wi, Wg, bf_, bi_, bg_, hb, fl, out);
}